// Round 1
// baseline (307.475 us; speedup 1.0000x reference)
//
#include <hip/hip_runtime.h>
#include <math.h>

#define M_TOTAL (32 * 8732)   // 279424 anchors; divisible by 64 (279424 = 64*4366)
#define C_CLS 81

struct Scalars {
    unsigned pos_num;
    float    loss_l;    // masked smooth-L1 sum
    float    pos_lc;    // sum of loss_c over positives
    unsigned b0;        // level-0 bucket of threshold
    unsigned k1;        // rank within bucket b0
    unsigned b1;
    unsigned k2;
    unsigned t;         // exact bit pattern of k-th largest con_neg
    unsigned r;         // number of elements == t that are selected
    float    sum_neg;   // sum of con_neg strictly greater than t
};

__device__ __forceinline__ float smooth_l1(float d) {
    float ad = fabsf(d);
    return (ad < 1.0f) ? 0.5f * ad * ad : ad - 0.5f;
}

// ---- Kernel A: per-anchor CE + smooth-L1 + con_neg + level-0 histogram ----
// 4 lanes per anchor, 64 anchors per 256-thread block.
__global__ __launch_bounds__(256) void kA(const float* __restrict__ ploc,
                                          const float* __restrict__ plabel,
                                          const float* __restrict__ gloc,
                                          const int* __restrict__ glabel,
                                          float* __restrict__ con_neg,
                                          unsigned* __restrict__ hist0,
                                          Scalars* sc) {
    __shared__ unsigned lh[2048];
    __shared__ float    red_l[64];
    __shared__ float    red_c[64];
    __shared__ unsigned red_p[64];

    const int tid = threadIdx.x;
    for (int i = tid; i < 2048; i += 256) lh[i] = 0;
    __syncthreads();

    const int l = tid & 3;       // lane within group
    const int g = tid >> 2;      // group (anchor) within block
    const int row = blockIdx.x * 64 + g;   // always < M_TOTAL (exact grid)

    const int gt = glabel[row];
    const int mask = gt > 0;

    // smooth-L1 over 4 coords: lane l handles coord l (coalesced 16B/group)
    float d = ploc[row * 4 + l] - gloc[row * 4 + l];
    float s = smooth_l1(d);
    s += __shfl_xor(s, 1);
    s += __shfl_xor(s, 2);

    // cross-entropy over 81 logits: lane l reads indices j*4+l, j=0..19 (+ idx 80 on lane 0)
    const float* rb = plabel + row * 81;
    float v[20];
    float m = -INFINITY;
#pragma unroll
    for (int j = 0; j < 20; ++j) {
        v[j] = rb[j * 4 + l];
        m = fmaxf(m, v[j]);
    }
    float v20 = 0.0f;
    if (l == 0) { v20 = rb[80]; m = fmaxf(m, v20); }
    m = fmaxf(m, __shfl_xor(m, 1));
    m = fmaxf(m, __shfl_xor(m, 2));

    float e = 0.0f;
#pragma unroll
    for (int j = 0; j < 20; ++j) e += expf(v[j] - m);
    if (l == 0) e += expf(v20 - m);
    e += __shfl_xor(e, 1);
    e += __shfl_xor(e, 2);
    const float lse = m + logf(e);

    const float x_gt   = rb[gt];
    const float loss_c = lse - x_gt;
    const float cn     = mask ? 0.0f : fmaxf(loss_c, 0.0f);

    if (l == 0) {
        con_neg[row] = cn;
        atomicAdd(&lh[__float_as_uint(cn) >> 21], 1u);
        red_p[g] = (unsigned)mask;
        red_l[g] = mask ? s : 0.0f;
        red_c[g] = mask ? loss_c : 0.0f;
    }
    __syncthreads();

    if (tid == 0) {
        unsigned pn = 0; float sl = 0.0f, sc2 = 0.0f;
        for (int i = 0; i < 64; ++i) { pn += red_p[i]; sl += red_l[i]; sc2 += red_c[i]; }
        if (pn) atomicAdd(&sc->pos_num, pn);
        atomicAdd(&sc->loss_l, sl);
        atomicAdd(&sc->pos_lc, sc2);
    }
    for (int i = tid; i < 2048; i += 256) {
        unsigned c = lh[i];
        if (c) atomicAdd(&hist0[i], c);
    }
}

// ---- Scan a histogram (suffix sums), find crossing bucket for rank k ----
__global__ __launch_bounds__(1024) void kScan(const unsigned* __restrict__ hist,
                                              int nbins, int level, Scalars* sc) {
    __shared__ unsigned ssum[1024];
    const int t = threadIdx.x;
    const unsigned h0 = (2 * t     < nbins) ? hist[2 * t]     : 0u;
    const unsigned h1 = (2 * t + 1 < nbins) ? hist[2 * t + 1] : 0u;
    ssum[t] = h0 + h1;
    __syncthreads();

    // inclusive suffix scan over pair sums (Hillis-Steele)
    for (int off = 1; off < 1024; off <<= 1) {
        unsigned val = ssum[t];
        unsigned add = (t + off < 1024) ? ssum[t + off] : 0u;
        __syncthreads();
        ssum[t] = val + add;
        __syncthreads();
    }

    unsigned k;
    if (level == 0) {
        unsigned pn = sc->pos_num;
        k = 3u * pn;
        if (k > (unsigned)M_TOTAL) k = (unsigned)M_TOTAL;
    } else if (level == 1) {
        k = sc->k1;
    } else {
        k = sc->k2;
    }

    const unsigned sA = ssum[t];                                // suffix(2t)
    const unsigned sB = sA - h0;                                // suffix(2t+1)
    const unsigned sC = (t + 1 < 1024) ? ssum[t + 1] : 0u;      // suffix(2t+2)

    // exactly one bin b satisfies suffix(b) >= k > suffix(b+1) when k >= 1
    if (2 * t < nbins && sA >= k && k > sB) {
        unsigned b = 2 * t, knext = k - sB;
        if (level == 0)      { sc->b0 = b; sc->k1 = knext; }
        else if (level == 1) { sc->b1 = b; sc->k2 = knext; }
        else                 { sc->t = (sc->b0 << 21) | (sc->b1 << 10) | b; sc->r = knext; }
    }
    if (2 * t + 1 < nbins && sB >= k && k > sC) {
        unsigned b = 2 * t + 1, knext = k - sC;
        if (level == 0)      { sc->b0 = b; sc->k1 = knext; }
        else if (level == 1) { sc->b1 = b; sc->k2 = knext; }
        else                 { sc->t = (sc->b0 << 21) | (sc->b1 << 10) | b; sc->r = knext; }
    }
}

// ---- Refinement histogram over elements matching the previous-level prefix ----
__global__ __launch_bounds__(256) void kHist(const float* __restrict__ con,
                                             unsigned* __restrict__ outHist,
                                             const Scalars* __restrict__ sc, int level) {
    __shared__ unsigned lh[2048];
    const int tid = threadIdx.x;
    const int nb = (level == 1) ? 2048 : 1024;
    for (int i = tid; i < nb; i += 256) lh[i] = 0;
    __syncthreads();

    const unsigned prefix = (level == 1) ? sc->b0 : ((sc->b0 << 11) | sc->b1);
    const int i = blockIdx.x * 256 + tid;
    if (i < M_TOTAL) {
        const unsigned u = __float_as_uint(con[i]);
        if (level == 1) {
            if ((u >> 21) == prefix) atomicAdd(&lh[(u >> 10) & 0x7FFu], 1u);
        } else {
            if ((u >> 10) == prefix) atomicAdd(&lh[u & 0x3FFu], 1u);
        }
    }
    __syncthreads();
    for (int i2 = tid; i2 < nb; i2 += 256) {
        unsigned c = lh[i2];
        if (c) atomicAdd(&outHist[i2], c);
    }
}

// ---- Sum con_neg strictly greater than threshold t ----
__global__ __launch_bounds__(256) void kSum(const float* __restrict__ con, Scalars* sc) {
    __shared__ float red[4];
    const unsigned t = sc->t;
    const int i = blockIdx.x * 256 + threadIdx.x;
    float v = 0.0f;
    if (i < M_TOTAL) {
        float x = con[i];
        if (__float_as_uint(x) > t) v = x;
    }
    for (int off = 1; off < 64; off <<= 1) v += __shfl_xor(v, off);
    if ((threadIdx.x & 63) == 0) red[threadIdx.x >> 6] = v;
    __syncthreads();
    if (threadIdx.x == 0) {
        float s2 = red[0] + red[1] + red[2] + red[3];
        if (s2 != 0.0f) atomicAdd(&sc->sum_neg, s2);
    }
}

__global__ void kFinal(const Scalars* __restrict__ sc, float* __restrict__ out) {
    if (threadIdx.x == 0 && blockIdx.x == 0) {
        const unsigned pn = sc->pos_num;
        float total = 0.0f;
        if (pn > 0) {
            const float tval  = __uint_as_float(sc->t);
            const float closs = sc->pos_lc + sc->sum_neg + (float)sc->r * tval;
            total = (sc->loss_l + closs) / (float)pn;
        }
        out[0] = total;
    }
}

extern "C" void kernel_launch(void* const* d_in, const int* in_sizes, int n_in,
                              void* d_out, int out_size, void* d_ws, size_t ws_size,
                              hipStream_t stream) {
    const float* ploc   = (const float*)d_in[0];
    const float* plabel = (const float*)d_in[1];
    const float* gloc   = (const float*)d_in[2];
    const int*   glabel = (const int*)d_in[3];
    float* out = (float*)d_out;

    char* ws = (char*)d_ws;
    float*    con   = (float*)ws;                                  // M floats
    unsigned* hist0 = (unsigned*)(ws + (size_t)M_TOTAL * 4);       // 2048
    unsigned* hist1 = hist0 + 2048;                                // 2048
    unsigned* hist2 = hist1 + 2048;                                // 1024
    Scalars*  sc    = (Scalars*)(hist2 + 1024);

    // zero histograms + scalars (ws is poisoned 0xAA before every launch)
    hipMemsetAsync(hist0, 0, (2048 + 2048 + 1024) * sizeof(unsigned) + sizeof(Scalars), stream);

    kA<<<M_TOTAL / 64, 256, 0, stream>>>(ploc, plabel, gloc, glabel, con, hist0, sc);
    kScan<<<1, 1024, 0, stream>>>(hist0, 2048, 0, sc);
    kHist<<<(M_TOTAL + 255) / 256, 256, 0, stream>>>(con, hist1, sc, 1);
    kScan<<<1, 1024, 0, stream>>>(hist1, 2048, 1, sc);
    kHist<<<(M_TOTAL + 255) / 256, 256, 0, stream>>>(con, hist2, sc, 2);
    kScan<<<1, 1024, 0, stream>>>(hist2, 1024, 2, sc);
    kSum<<<(M_TOTAL + 255) / 256, 256, 0, stream>>>(con, sc);
    kFinal<<<1, 64, 0, stream>>>(sc, out);
}